// Round 13
// baseline (178.767 us; speedup 1.0000x reference)
//
#include <hip/hip_runtime.h>

#define SPLITK 256
#define FC1_K 55815

// ============ conv1 + relu + pool1 fused (v9: hoisted stage offsets, interior fast path) ============
// in (128,3,250,250) --5x5 s2 p1--> conv(128,6,124,124) --relu--2x2 s1 pool--> out (128,6,123,123)
// Wave owns 8 conv rows; stages its own 19x68 strip per channel (region 1292 floats, plain layout).
// Stage addressing (y,x walk + bounds) computed ONCE into off[21]/msk, reused for all 3 channels.
// Interior blocks (tr,tc in {1,2}) skip all masking via a block-uniform branch.
__global__ __launch_bounds__(256) void conv1f_k(const float* __restrict__ in,
                                                const float* __restrict__ w,
                                                const float* __restrict__ bias,
                                                float* __restrict__ out) {
    __shared__ float sbuf[5744];  // 4 wave regions x 1292 = 5168, + halo [3][6][32] = 576
    const int tc = blockIdx.x, tr = blockIdx.y, b = blockIdx.z;
    const int pr0 = tr * 31, pc0 = tc * 31;
    const int tid = threadIdx.x;
    const int wv = tid >> 6, lane = tid & 63;
    const int i = tid >> 4, j = tid & 15;   // block-level quad coords (i = 4*wv + il)
    const int il = i & 3;                   // wave-local quad row
    float* wreg = sbuf + wv * 1292;
    float* halo = sbuf + 5168;
    const float* inb = in + (size_t)b * 187500;
    const int irw = 2 * pr0 - 1 + 16 * wv;  // first input row of this wave's window
    const int ic0 = 2 * pc0 - 1;
    const bool safe = (tr == 1 || tr == 2) && (tc == 1 || tc == 2);  // window fully in-bounds

    // ---- one-time stage addressing (reused by all 3 channels)
    int off[21];
    unsigned msk = 0u;
    {
        int y = 0, x = lane;
        #pragma unroll
        for (int it = 0; it < 21; ++it) {
            int gr = irw + y, gc = ic0 + x;
            bool valid = ((unsigned)gr < 250u) && ((unsigned)gc < 250u) && (it < 20 || lane < 12);
            off[it] = valid ? (gr * 250 + gc) : 0;
            msk |= (valid ? 1u : 0u) << it;
            x += 64; if (x >= 68) { x -= 68; ++y; }   // +256 threads == 3*68 + 52 per 4 lanesteps
        }
    }

    float acc[6][2][2];
    #pragma unroll
    for (int o = 0; o < 6; ++o) {
        float bv = bias[o];
        acc[o][0][0] = bv; acc[o][0][1] = bv; acc[o][1][0] = bv; acc[o][1][1] = bv;
    }

    for (int c = 0; c < 3; ++c) {
        const float* cp = inb + c * 62500;
        // ---- wave-private stage (no barriers; wave-internal waitcnt orders LDS)
        if (safe) {
            #pragma unroll
            for (int it = 0; it < 20; ++it) wreg[lane + it * 64] = cp[off[it]];
            if (lane < 12) wreg[1280 + lane] = cp[off[20]];
        } else {
            #pragma unroll
            for (int it = 0; it < 20; ++it) {
                float v = 0.0f;
                if ((msk >> it) & 1u) v = cp[off[it]];
                wreg[lane + it * 64] = v;
            }
            if (lane < 12) {
                float v = 0.0f;
                if ((msk >> 20) & 1u) v = cp[off[20]];
                wreg[1280 + lane] = v;
            }
        }
        // ---- compute from own region
        #pragma unroll
        for (int wr = 0; wr < 7; ++wr) {
            const float* rp = &wreg[(4 * il + wr) * 68 + 4 * j];
            float row[7];
            float4 v4 = *(const float4*)rp;
            float2 v2 = *(const float2*)(rp + 4);
            row[0] = v4.x; row[1] = v4.y; row[2] = v4.z; row[3] = v4.w;
            row[4] = v2.x; row[5] = v2.y; row[6] = rp[6];
            #pragma unroll
            for (int o = 0; o < 6; ++o) {
                #pragma unroll
                for (int kw = 0; kw < 5; ++kw) {
                    if (wr <= 4) {
                        float wv_ = w[o * 75 + c * 25 + wr * 5 + kw];
                        acc[o][0][0] = fmaf(row[kw], wv_, acc[o][0][0]);
                        acc[o][0][1] = fmaf(row[kw + 2], wv_, acc[o][0][1]);
                    }
                    if (wr >= 2) {
                        float wv_ = w[o * 75 + c * 25 + (wr - 2) * 5 + kw];
                        acc[o][1][0] = fmaf(row[kw], wv_, acc[o][1][0]);
                        acc[o][1][1] = fmaf(row[kw + 2], wv_, acc[o][1][1]);
                    }
                }
            }
        }
    }

    // ---- halo handoff: waves 1..3 publish their first conv row (raw, pre-relu)
    if (il == 0 && wv > 0) {
        #pragma unroll
        for (int o = 0; o < 6; ++o) {
            halo[(wv - 1) * 192 + o * 32 + 2 * j]     = acc[o][0][0];
            halo[(wv - 1) * 192 + o * 32 + 2 * j + 1] = acc[o][0][1];
        }
    }
    __syncthreads();  // the only barrier

    // ---- pool 2x2 s1 from registers (+shfl, +halo for wave-boundary row), relu after max
    const int gr0 = pr0 + 2 * i, gc0 = pc0 + 2 * j;
    const bool r1in = (2 * i + 1 < 31) && (gr0 + 1 < 123);
    const bool c1in = (2 * j + 1 < 31) && (gc0 + 1 < 123);
    const bool r0in = gr0 < 123, c0in = gc0 < 123;
    const bool lastrow = (il == 3);
    const int hb = (wv < 2 ? wv : 2) * 192;  // clamp; wv=3 never uses halo values
    #pragma unroll
    for (int o = 0; o < 6; ++o) {
        float a00 = acc[o][0][0], a01 = acc[o][0][1];
        float a10 = acc[o][1][0], a11 = acc[o][1][1];
        float r0c2 = __shfl(a00, lane + 1);
        float r1c2 = __shfl(a10, lane + 1);
        float s20  = __shfl(a00, lane + 16);
        float s21  = __shfl(a01, lane + 16);
        float s22  = __shfl(a00, lane + 17);
        int hbo = hb + o * 32;
        float h0 = halo[hbo + 2 * j];
        float h1 = halo[hbo + 2 * j + 1];
        float h2 = halo[hbo + (2 * j + 2 > 31 ? 31 : 2 * j + 2)];
        float r2c0 = lastrow ? h0 : s20;
        float r2c1 = lastrow ? h1 : s21;
        float r2c2 = lastrow ? h2 : s22;
        float* orow = out + ((size_t)(b * 6 + o) * 123 + gr0) * 123 + gc0;
        if (r0in && c0in) orow[0]   = fmaxf(fmaxf(fmaxf(a00, a01), fmaxf(a10, a11)), 0.0f);
        if (r0in && c1in) orow[1]   = fmaxf(fmaxf(fmaxf(a01, r0c2), fmaxf(a11, r1c2)), 0.0f);
        if (r1in && c0in) orow[123] = fmaxf(fmaxf(fmaxf(a10, a11), fmaxf(r2c0, r2c1)), 0.0f);
        if (r1in && c1in) orow[124] = fmaxf(fmaxf(fmaxf(a11, r1c2), fmaxf(r2c1, r2c2)), 0.0f);
    }
}

// ============ conv2 + relu + pool2 fused (v5: hoisted stage offsets, interior fast path) ============
// in (128,6,123,123) --3x3 s2 p1--> conv(128,15,62,62) --relu--pool--> out (128,15,61,61)
__global__ __launch_bounds__(256) void conv2f_k(const float* __restrict__ in,
                                                const float* __restrict__ w,
                                                const float* __restrict__ bias,
                                                float* __restrict__ out) {
    __shared__ float smem[2000];  // 4 wave regions x 320 + halo [3][15][16]=720
    const int tc = blockIdx.x, tr = blockIdx.y, b = blockIdx.z;
    const int pr0 = tr * 15, pc0 = tc * 15;
    const int tid = threadIdx.x;
    const int wv = tid >> 6, lane = tid & 63;
    const int ti = tid >> 4, tj = tid & 15;
    const int tl = ti & 3;
    float* wreg = smem + wv * 320;
    float* halo = smem + 1280;
    const float* inb = in + (size_t)b * 6 * 15129;
    const int irw = 2 * pr0 - 1 + 8 * wv;
    const int ic0 = 2 * pc0 - 1;
    const bool safe = (tr >= 1 && tr <= 3) && (tc >= 1 && tc <= 3);

    int off[5];
    unsigned msk = 0u;
    {
        int y = (lane >= 34) ? 1 : 0;
        int x = lane - 34 * y;
        #pragma unroll
        for (int it = 0; it < 5; ++it) {
            int gr = irw + y, gc = ic0 + x;
            bool valid = ((unsigned)gr < 123u) && ((unsigned)gc < 123u);
            off[it] = valid ? (gr * 123 + gc) : 0;
            msk |= (valid ? 1u : 0u) << it;
            x += 30; ++y;
            if (x >= 34) { x -= 34; ++y; }
        }
    }

    float acc[15];
    #pragma unroll
    for (int o = 0; o < 15; ++o) acc[o] = bias[o];

    for (int c = 0; c < 6; ++c) {
        const float* cp = inb + c * 15129;
        if (safe) {
            #pragma unroll
            for (int it = 0; it < 5; ++it) wreg[lane + it * 64] = cp[off[it]];
        } else {
            #pragma unroll
            for (int it = 0; it < 5; ++it) {
                float v = 0.0f;
                if ((msk >> it) & 1u) v = cp[off[it]];
                wreg[lane + it * 64] = v;
            }
        }
        #pragma unroll
        for (int kh = 0; kh < 3; ++kh) {
            const float* r = &wreg[(2 * tl + kh) * 34 + 2 * tj];
            float a0 = r[0], a1 = r[1], a2 = r[2];
            #pragma unroll
            for (int o = 0; o < 15; ++o) {
                const float* wr_ = &w[o * 54 + c * 9 + kh * 3];
                acc[o] = fmaf(a0, wr_[0], acc[o]);
                acc[o] = fmaf(a1, wr_[1], acc[o]);
                acc[o] = fmaf(a2, wr_[2], acc[o]);
            }
        }
    }

    if (tl == 0 && wv > 0) {
        #pragma unroll
        for (int o = 0; o < 15; ++o)
            halo[(wv - 1) * 240 + o * 16 + tj] = acc[o];
    }
    __syncthreads();  // the only barrier

    const int gr = pr0 + ti, gc = pc0 + tj;
    const bool valid = (ti < 15) && (tj < 15) && (gr < 61) && (gc < 61);
    const bool lastrow = (tl == 3);
    const int hb = (wv < 2 ? wv : 2) * 240;
    #pragma unroll
    for (int o = 0; o < 15; ++o) {
        float c00 = acc[o];
        float c01 = __shfl(acc[o], lane + 1);
        float s10 = __shfl(acc[o], lane + 16);
        float s11 = __shfl(acc[o], lane + 17);
        float h10 = halo[hb + o * 16 + tj];
        float h11 = halo[hb + o * 16 + (tj + 1 > 15 ? 15 : tj + 1)];
        float c10 = lastrow ? h10 : s10;
        float c11 = lastrow ? h11 : s11;
        float m = fmaxf(fmaxf(fmaxf(c00, c01), fmaxf(c10, c11)), 0.0f);
        if (valid) out[((size_t)(b * 15 + o) * 61 + gr) * 61 + gc] = m;
    }
}

// ---------------- fc1 v3: split-K x MN-quadrant GEMM, double-buffered, 1 barrier/iter. (unchanged)
__global__ __launch_bounds__(256) void fc1_k(const float* __restrict__ X,
                                             const float* __restrict__ W,
                                             float* __restrict__ P) {
    __shared__ float Xs[2][16][68];
    __shared__ float Ws[2][16][68];
    const int K = FC1_K;
    const int chunk = (K + SPLITK - 1) / SPLITK;  // 219
    const int s = blockIdx.x;
    const int mh = blockIdx.y >> 1, nh = blockIdx.y & 1;
    const int m0 = mh * 64, n0 = nh * 60;
    int ks = s * chunk;
    int ke = min(ks + chunk, K);
    int tid = threadIdx.x;
    int tx = tid & 15, ty = tid >> 4;
    const int kk_ = tid & 15, r0_ = tid >> 4;
    float acc[4][4];
    #pragma unroll
    for (int ii = 0; ii < 4; ++ii)
        #pragma unroll
        for (int jj = 0; jj < 4; ++jj) acc[ii][jj] = 0.0f;

    float nx[4], nw[4];
    auto ld = [&](int k0n) {
        int krem = ke - k0n;
        int k = k0n + kk_;
        bool kv = kk_ < krem;
        #pragma unroll
        for (int it = 0; it < 4; ++it) {
            int r = r0_ + it * 16;
            nx[it] = kv ? X[(size_t)(m0 + r) * K + k] : 0.0f;
            nw[it] = (kv && r < 60) ? W[(size_t)(n0 + r) * K + k] : 0.0f;
        }
    };
    auto st = [&](int buf) {
        #pragma unroll
        for (int it = 0; it < 4; ++it) {
            int r = r0_ + it * 16;
            Xs[buf][kk_][r] = nx[it];
            Ws[buf][kk_][r] = nw[it];
        }
    };

    if (ks < ke) { ld(ks); st(0); }
    int cur = 0;
    for (int k0 = ks; k0 < ke; k0 += 16) {
        __syncthreads();                    // buf[cur] staged
        bool hn = (k0 + 16) < ke;
        if (hn) ld(k0 + 16);                // issue next-chunk loads (hide under FMA)
        #pragma unroll
        for (int kk = 0; kk < 16; ++kk) {
            float4 a = *(const float4*)&Xs[cur][kk][ty * 4];
            float4 bb = *(const float4*)&Ws[cur][kk][tx * 4];
            float av[4] = {a.x, a.y, a.z, a.w};
            float bv[4] = {bb.x, bb.y, bb.z, bb.w};
            #pragma unroll
            for (int ii = 0; ii < 4; ++ii)
                #pragma unroll
                for (int jj = 0; jj < 4; ++jj)
                    acc[ii][jj] = fmaf(av[ii], bv[jj], acc[ii][jj]);
        }
        if (hn) st(cur ^ 1);                // buf[cur^1] readers finished before this iter's barrier
        cur ^= 1;
    }
    float* Pp = P + (size_t)s * 15360;
    #pragma unroll
    for (int ii = 0; ii < 4; ++ii) {
        int m = m0 + ty * 4 + ii;
        #pragma unroll
        for (int jj = 0; jj < 4; ++jj) {
            int nn = tx * 4 + jj;
            if (nn < 60) Pp[m * 120 + n0 + nn] = acc[ii][jj];
        }
    }
}

// ---------------- tail v2: coalesced partial reduce + fc2 + fc3 + quantum head (unchanged)
__global__ __launch_bounds__(256) void tail_k(const float* __restrict__ P,
                                              const float* __restrict__ f1b,
                                              const float* __restrict__ f2w,
                                              const float* __restrict__ f2b,
                                              const float* __restrict__ f3w,
                                              const float* __restrict__ f3b,
                                              const float* __restrict__ qp,
                                              float* __restrict__ out) {
    __shared__ float red[2][120];
    __shared__ float x1[120];
    __shared__ float x2[84];
    int b = blockIdx.x, tid = threadIdx.x;
    if (tid < 240) {
        int part = tid / 120;
        int n = tid - part * 120;
        const float* p = P + (size_t)b * 120 + n;
        float acc = 0.0f;
        #pragma unroll 8
        for (int s = part; s < SPLITK; s += 2)
            acc += p[(size_t)s * 15360];
        red[part][n] = acc;
    }
    __syncthreads();
    if (tid < 120)
        x1[tid] = fmaxf(red[0][tid] + red[1][tid] + f1b[tid], 0.0f);
    __syncthreads();
    if (tid < 84) {
        float acc = f2b[tid];
        const float* wr = f2w + tid * 120;
        #pragma unroll 4
        for (int n = 0; n < 120; ++n) acc = fmaf(x1[n], wr[n], acc);
        x2[tid] = fmaxf(acc, 0.0f);
    }
    __syncthreads();
    if (tid == 0) {
        float x = f3b[0];
        for (int m = 0; m < 84; ++m) x = fmaf(x2[m], f3w[m], x);
        float sr[16], si[16];
        #pragma unroll
        for (int i = 0; i < 16; ++i) { sr[i] = 0.0f; si[i] = 0.0f; }
        sr[0] = 1.0f;
        float c0 = cosf(0.5f * x), s0 = sinf(0.5f * x);
        #pragma unroll
        for (int w = 0; w < 4; ++w) {
            int mask = 8 >> w;
            #pragma unroll
            for (int idx = 0; idx < 16; ++idx) {
                if (idx & mask) continue;
                int i1 = idx | mask;
                float a0r = sr[idx], a0i = si[idx], a1r = sr[i1], a1i = si[i1];
                sr[idx] = c0 * a0r - s0 * a1r;  si[idx] = c0 * a0i - s0 * a1i;
                sr[i1]  = s0 * a0r + c0 * a1r;  si[i1]  = s0 * a0i + c0 * a1i;
            }
        }
        for (int layer = 0; layer < 2; ++layer) {
            #pragma unroll
            for (int w = 0; w < 4; ++w) {
                int gi = (layer * 4 + w) * 3;
                float phi = qp[gi], th = qp[gi + 1], om = qp[gi + 2];
                float hs = 0.5f * (phi + om), hd = 0.5f * (phi - om);
                float ct = cosf(0.5f * th), st = sinf(0.5f * th);
                float chs = cosf(hs), shs = sinf(hs);
                float chd = cosf(hd), shd = sinf(hd);
                float m00r = chs * ct,  m00i = -shs * ct;
                float m01r = -chd * st, m01i = -shd * st;
                float m10r = chd * st,  m10i = -shd * st;
                float m11r = chs * ct,  m11i = shs * ct;
                int mask = 8 >> w;
                #pragma unroll
                for (int idx = 0; idx < 16; ++idx) {
                    if (idx & mask) continue;
                    int i1 = idx | mask;
                    float a0r = sr[idx], a0i = si[idx], a1r = sr[i1], a1i = si[i1];
                    sr[idx] = m00r * a0r - m00i * a0i + m01r * a1r - m01i * a1i;
                    si[idx] = m00r * a0i + m00i * a0r + m01r * a1i + m01i * a1r;
                    sr[i1]  = m10r * a0r - m10i * a0i + m11r * a1r - m11i * a1i;
                    si[i1]  = m10r * a0i + m10i * a0r + m11r * a1i + m11i * a1r;
                }
            }
            #pragma unroll
            for (int cw = 0; cw < 3; ++cw) {
                int cm = 8 >> cw, tm = 8 >> (cw + 1);
                #pragma unroll
                for (int idx = 0; idx < 16; ++idx) {
                    if ((idx & cm) && !(idx & tm)) {
                        int i1 = idx | tm;
                        float tr = sr[idx]; sr[idx] = sr[i1]; sr[i1] = tr;
                        float ti = si[idx]; si[idx] = si[i1]; si[i1] = ti;
                    }
                }
            }
        }
        float q = 0.0f;
        #pragma unroll
        for (int idx = 0; idx < 16; ++idx) {
            float p2 = sr[idx] * sr[idx] + si[idx] * si[idx];
            q += (idx < 8) ? p2 : -p2;
        }
        float pr = 0.5f * (q + 1.0f);
        out[2 * b] = pr;
        out[2 * b + 1] = 1.0f - pr;
    }
}

extern "C" void kernel_launch(void* const* d_in, const int* in_sizes, int n_in,
                              void* d_out, int out_size, void* d_ws, size_t ws_size,
                              hipStream_t stream) {
    const float* inp = (const float*)d_in[0];
    const float* c1w = (const float*)d_in[1];
    const float* c1b = (const float*)d_in[2];
    const float* c2w = (const float*)d_in[3];
    const float* c2b = (const float*)d_in[4];
    const float* f1w = (const float*)d_in[5];
    const float* f1b = (const float*)d_in[6];
    const float* f2w = (const float*)d_in[7];
    const float* f2b = (const float*)d_in[8];
    const float* f3w = (const float*)d_in[9];
    const float* f3b = (const float*)d_in[10];
    const float* qp  = (const float*)d_in[11];
    float* out = (float*)d_out;
    float* ws = (float*)d_ws;

    // ws layout (floats):
    //   B (pool1 out) @ 0          : 128*6*123*123  = 11,619,072
    //   D (pool2 out) @ 11,619,072 : 128*15*61*61   =  7,144,320
    //   P (fc1 part.) @ 18,763,392 : SPLITK*128*120 =  3,932,160   (total 90.8 MB)
    float* B = ws;
    float* D = ws + 11619072;
    float* P = ws + 18763392;

    conv1f_k<<<dim3(4, 4, 128), 256, 0, stream>>>(inp, c1w, c1b, B);
    conv2f_k<<<dim3(5, 5, 128), 256, 0, stream>>>(B, c2w, c2b, D);
    fc1_k<<<dim3(SPLITK, 4), 256, 0, stream>>>(D, f1w, P);
    tail_k<<<128, 256, 0, stream>>>(P, f1b, f2w, f2b, f3w, f3b, qp, out);
}

// Round 14
// 163.472 us; speedup vs baseline: 1.0936x; 1.0936x over previous
//
#include <hip/hip_runtime.h>

#define SPLITK 256
#define FC1_K 55815

// ============ conv1 + relu + pool1 fused (v6 r10-verbatim: single-buffer pipeline, natural VGPR) ============
// in (128,3,250,250) --5x5 s2 p1--> conv (128,6,124,124) --relu--2x2 s1 pool--> out (128,6,123,123)
// Best measured: 73.2 us (r10). NO launch_bounds min-waves (spills); NO hoisted off[21] (r13: starved
// load batching, 115 us); NO xor swizzle (r12: +VALU, conflicts only 4% of wave time).
__global__ __launch_bounds__(256) void conv1f_k(const float* __restrict__ in,
                                                const float* __restrict__ w,
                                                const float* __restrict__ bias,
                                                float* __restrict__ out) {
    __shared__ float sbuf[4608];  // stage buffer; later stash [3][32][33]=3168 aliases
    const int tc = blockIdx.x, tr = blockIdx.y, b = blockIdx.z;
    const int pr0 = tr * 31, pc0 = tc * 31;
    const int tid = threadIdx.x;
    const int i = tid >> 4, j = tid & 15;
    const float* inb = in + (size_t)b * 187500;
    const int ir0 = 2 * pr0 - 1, ic0 = 2 * pc0 - 1;

    float acc[6][2][2];
    #pragma unroll
    for (int o = 0; o < 6; ++o) {
        float bv = bias[o];
        acc[o][0][0] = bv; acc[o][0][1] = bv; acc[o][1][0] = bv; acc[o][1][1] = bv;
    }

    float stg[18];
    auto load_ch = [&](int c) {
        const float* cp = inb + c * 62500;
        int y = tid / 68;
        int x = tid - y * 68;
        #pragma unroll
        for (int it = 0; it < 18; ++it) {
            int gr = ir0 + y, gc = ic0 + x;
            float v = 0.0f;
            if ((unsigned)gr < 250u && (unsigned)gc < 250u)
                v = cp[gr * 250 + gc];
            stg[it] = v;
            x += 52; y += 3;                 // +256 == 3*68 + 52
            if (x >= 68) { x -= 68; ++y; }
        }
    };
    auto write_ch = [&]() {
        #pragma unroll
        for (int it = 0; it < 18; ++it) sbuf[tid + it * 256] = stg[it];
    };
    auto compute_ch = [&](int c) {
        #pragma unroll
        for (int wr = 0; wr < 7; ++wr) {
            const float* rp = &sbuf[(4 * i + wr) * 68 + 4 * j];
            float row[7];
            float4 v4 = *(const float4*)rp;
            float2 v2 = *(const float2*)(rp + 4);
            row[0] = v4.x; row[1] = v4.y; row[2] = v4.z; row[3] = v4.w;
            row[4] = v2.x; row[5] = v2.y; row[6] = rp[6];
            #pragma unroll
            for (int o = 0; o < 6; ++o) {
                #pragma unroll
                for (int kw = 0; kw < 5; ++kw) {
                    if (wr <= 4) {
                        float wv = w[o * 75 + c * 25 + wr * 5 + kw];
                        acc[o][0][0] = fmaf(row[kw], wv, acc[o][0][0]);
                        acc[o][0][1] = fmaf(row[kw + 2], wv, acc[o][0][1]);
                    }
                    if (wr >= 2) {
                        float wv = w[o * 75 + c * 25 + (wr - 2) * 5 + kw];
                        acc[o][1][0] = fmaf(row[kw], wv, acc[o][1][0]);
                        acc[o][1][1] = fmaf(row[kw + 2], wv, acc[o][1][1]);
                    }
                }
            }
        }
    };

    load_ch(0); write_ch();
    __syncthreads();
    load_ch(1); compute_ch(0);
    __syncthreads();          // ch0 reads done
    write_ch();
    __syncthreads();          // ch1 staged
    load_ch(2); compute_ch(1);
    __syncthreads();          // ch1 reads done
    write_ch();
    __syncthreads();          // ch2 staged
    compute_ch(2);
    __syncthreads();          // all stage reads done -> safe to alias stash

    // stash + pool, 2 groups of 3 output channels ([3][32][33] fits in 4608)
    const int gr0 = pr0 + 2 * i, gc0 = pc0 + 2 * j;
    const bool r1in = (2 * i + 1 < 31) && (gr0 + 1 < 123);
    const bool c1in = (2 * j + 1 < 31) && (gc0 + 1 < 123);
    const bool r0in = gr0 < 123, c0in = gc0 < 123;
    #pragma unroll
    for (int g = 0; g < 2; ++g) {
        #pragma unroll
        for (int oo = 0; oo < 3; ++oo)
            #pragma unroll
            for (int di = 0; di < 2; ++di)
                #pragma unroll
                for (int dj = 0; dj < 2; ++dj)
                    sbuf[(oo * 32 + 2 * i + di) * 33 + (2 * j + dj)] =
                        fmaxf(acc[g * 3 + oo][di][dj], 0.0f);
        __syncthreads();
        #pragma unroll
        for (int oo = 0; oo < 3; ++oo) {
            int o = g * 3 + oo;
            const float* p0 = &sbuf[(oo * 32 + 2 * i) * 33 + 2 * j];
            float c00 = p0[0],  c01 = p0[1],  c02 = p0[2];
            float c10 = p0[33], c11 = p0[34], c12 = p0[35];
            float c20 = p0[66], c21 = p0[67], c22 = p0[68];
            float* orow = out + ((size_t)(b * 6 + o) * 123 + gr0) * 123 + gc0;
            if (r0in && c0in) orow[0]   = fmaxf(fmaxf(c00, c01), fmaxf(c10, c11));
            if (r0in && c1in) orow[1]   = fmaxf(fmaxf(c01, c02), fmaxf(c11, c12));
            if (r1in && c0in) orow[123] = fmaxf(fmaxf(c10, c11), fmaxf(c20, c21));
            if (r1in && c1in) orow[124] = fmaxf(fmaxf(c11, c12), fmaxf(c21, c22));
        }
        __syncthreads();
    }
}

// ============ conv2 + relu + pool2 fused (v5 r13-verbatim: hoisted stage offsets) ============
// in (128,6,123,123) --3x3 s2 p1--> conv(128,15,62,62) --relu--pool--> out (128,15,61,61)
// off[5] hoist saved ~25 us vs per-channel y/x walk (r12->r13 non-conv1f delta).
__global__ __launch_bounds__(256) void conv2f_k(const float* __restrict__ in,
                                                const float* __restrict__ w,
                                                const float* __restrict__ bias,
                                                float* __restrict__ out) {
    __shared__ float smem[2000];  // 4 wave regions x 320 + halo [3][15][16]=720
    const int tc = blockIdx.x, tr = blockIdx.y, b = blockIdx.z;
    const int pr0 = tr * 15, pc0 = tc * 15;
    const int tid = threadIdx.x;
    const int wv = tid >> 6, lane = tid & 63;
    const int ti = tid >> 4, tj = tid & 15;
    const int tl = ti & 3;
    float* wreg = smem + wv * 320;
    float* halo = smem + 1280;
    const float* inb = in + (size_t)b * 6 * 15129;
    const int irw = 2 * pr0 - 1 + 8 * wv;
    const int ic0 = 2 * pc0 - 1;
    const bool safe = (tr >= 1 && tr <= 3) && (tc >= 1 && tc <= 3);

    int off[5];
    unsigned msk = 0u;
    {
        int y = (lane >= 34) ? 1 : 0;
        int x = lane - 34 * y;
        #pragma unroll
        for (int it = 0; it < 5; ++it) {
            int gr = irw + y, gc = ic0 + x;
            bool valid = ((unsigned)gr < 123u) && ((unsigned)gc < 123u);
            off[it] = valid ? (gr * 123 + gc) : 0;
            msk |= (valid ? 1u : 0u) << it;
            x += 30; ++y;
            if (x >= 34) { x -= 34; ++y; }
        }
    }

    float acc[15];
    #pragma unroll
    for (int o = 0; o < 15; ++o) acc[o] = bias[o];

    for (int c = 0; c < 6; ++c) {
        const float* cp = inb + c * 15129;
        if (safe) {
            #pragma unroll
            for (int it = 0; it < 5; ++it) wreg[lane + it * 64] = cp[off[it]];
        } else {
            #pragma unroll
            for (int it = 0; it < 5; ++it) {
                float v = 0.0f;
                if ((msk >> it) & 1u) v = cp[off[it]];
                wreg[lane + it * 64] = v;
            }
        }
        #pragma unroll
        for (int kh = 0; kh < 3; ++kh) {
            const float* r = &wreg[(2 * tl + kh) * 34 + 2 * tj];
            float a0 = r[0], a1 = r[1], a2 = r[2];
            #pragma unroll
            for (int o = 0; o < 15; ++o) {
                const float* wr_ = &w[o * 54 + c * 9 + kh * 3];
                acc[o] = fmaf(a0, wr_[0], acc[o]);
                acc[o] = fmaf(a1, wr_[1], acc[o]);
                acc[o] = fmaf(a2, wr_[2], acc[o]);
            }
        }
    }

    if (tl == 0 && wv > 0) {
        #pragma unroll
        for (int o = 0; o < 15; ++o)
            halo[(wv - 1) * 240 + o * 16 + tj] = acc[o];
    }
    __syncthreads();  // the only barrier

    const int gr = pr0 + ti, gc = pc0 + tj;
    const bool valid = (ti < 15) && (tj < 15) && (gr < 61) && (gc < 61);
    const bool lastrow = (tl == 3);
    const int hb = (wv < 2 ? wv : 2) * 240;
    #pragma unroll
    for (int o = 0; o < 15; ++o) {
        float c00 = acc[o];
        float c01 = __shfl(acc[o], lane + 1);
        float s10 = __shfl(acc[o], lane + 16);
        float s11 = __shfl(acc[o], lane + 17);
        float h10 = halo[hb + o * 16 + tj];
        float h11 = halo[hb + o * 16 + (tj + 1 > 15 ? 15 : tj + 1)];
        float c10 = lastrow ? h10 : s10;
        float c11 = lastrow ? h11 : s11;
        float m = fmaxf(fmaxf(fmaxf(c00, c01), fmaxf(c10, c11)), 0.0f);
        if (valid) out[((size_t)(b * 15 + o) * 61 + gr) * 61 + gc] = m;
    }
}

// ---------------- fc1 v3: split-K x MN-quadrant GEMM, double-buffered, 1 barrier/iter. (unchanged)
__global__ __launch_bounds__(256) void fc1_k(const float* __restrict__ X,
                                             const float* __restrict__ W,
                                             float* __restrict__ P) {
    __shared__ float Xs[2][16][68];
    __shared__ float Ws[2][16][68];
    const int K = FC1_K;
    const int chunk = (K + SPLITK - 1) / SPLITK;  // 219
    const int s = blockIdx.x;
    const int mh = blockIdx.y >> 1, nh = blockIdx.y & 1;
    const int m0 = mh * 64, n0 = nh * 60;
    int ks = s * chunk;
    int ke = min(ks + chunk, K);
    int tid = threadIdx.x;
    int tx = tid & 15, ty = tid >> 4;
    const int kk_ = tid & 15, r0_ = tid >> 4;
    float acc[4][4];
    #pragma unroll
    for (int ii = 0; ii < 4; ++ii)
        #pragma unroll
        for (int jj = 0; jj < 4; ++jj) acc[ii][jj] = 0.0f;

    float nx[4], nw[4];
    auto ld = [&](int k0n) {
        int krem = ke - k0n;
        int k = k0n + kk_;
        bool kv = kk_ < krem;
        #pragma unroll
        for (int it = 0; it < 4; ++it) {
            int r = r0_ + it * 16;
            nx[it] = kv ? X[(size_t)(m0 + r) * K + k] : 0.0f;
            nw[it] = (kv && r < 60) ? W[(size_t)(n0 + r) * K + k] : 0.0f;
        }
    };
    auto st = [&](int buf) {
        #pragma unroll
        for (int it = 0; it < 4; ++it) {
            int r = r0_ + it * 16;
            Xs[buf][kk_][r] = nx[it];
            Ws[buf][kk_][r] = nw[it];
        }
    };

    if (ks < ke) { ld(ks); st(0); }
    int cur = 0;
    for (int k0 = ks; k0 < ke; k0 += 16) {
        __syncthreads();                    // buf[cur] staged
        bool hn = (k0 + 16) < ke;
        if (hn) ld(k0 + 16);                // issue next-chunk loads (hide under FMA)
        #pragma unroll
        for (int kk = 0; kk < 16; ++kk) {
            float4 a = *(const float4*)&Xs[cur][kk][ty * 4];
            float4 bb = *(const float4*)&Ws[cur][kk][tx * 4];
            float av[4] = {a.x, a.y, a.z, a.w};
            float bv[4] = {bb.x, bb.y, bb.z, bb.w};
            #pragma unroll
            for (int ii = 0; ii < 4; ++ii)
                #pragma unroll
                for (int jj = 0; jj < 4; ++jj)
                    acc[ii][jj] = fmaf(av[ii], bv[jj], acc[ii][jj]);
        }
        if (hn) st(cur ^ 1);                // buf[cur^1] readers finished before this iter's barrier
        cur ^= 1;
    }
    float* Pp = P + (size_t)s * 15360;
    #pragma unroll
    for (int ii = 0; ii < 4; ++ii) {
        int m = m0 + ty * 4 + ii;
        #pragma unroll
        for (int jj = 0; jj < 4; ++jj) {
            int nn = tx * 4 + jj;
            if (nn < 60) Pp[m * 120 + n0 + nn] = acc[ii][jj];
        }
    }
}

// ---------------- tail v2: coalesced partial reduce + fc2 + fc3 + quantum head (unchanged)
__global__ __launch_bounds__(256) void tail_k(const float* __restrict__ P,
                                              const float* __restrict__ f1b,
                                              const float* __restrict__ f2w,
                                              const float* __restrict__ f2b,
                                              const float* __restrict__ f3w,
                                              const float* __restrict__ f3b,
                                              const float* __restrict__ qp,
                                              float* __restrict__ out) {
    __shared__ float red[2][120];
    __shared__ float x1[120];
    __shared__ float x2[84];
    int b = blockIdx.x, tid = threadIdx.x;
    if (tid < 240) {
        int part = tid / 120;
        int n = tid - part * 120;
        const float* p = P + (size_t)b * 120 + n;
        float acc = 0.0f;
        #pragma unroll 8
        for (int s = part; s < SPLITK; s += 2)
            acc += p[(size_t)s * 15360];
        red[part][n] = acc;
    }
    __syncthreads();
    if (tid < 120)
        x1[tid] = fmaxf(red[0][tid] + red[1][tid] + f1b[tid], 0.0f);
    __syncthreads();
    if (tid < 84) {
        float acc = f2b[tid];
        const float* wr = f2w + tid * 120;
        #pragma unroll 4
        for (int n = 0; n < 120; ++n) acc = fmaf(x1[n], wr[n], acc);
        x2[tid] = fmaxf(acc, 0.0f);
    }
    __syncthreads();
    if (tid == 0) {
        float x = f3b[0];
        for (int m = 0; m < 84; ++m) x = fmaf(x2[m], f3w[m], x);
        float sr[16], si[16];
        #pragma unroll
        for (int i = 0; i < 16; ++i) { sr[i] = 0.0f; si[i] = 0.0f; }
        sr[0] = 1.0f;
        float c0 = cosf(0.5f * x), s0 = sinf(0.5f * x);
        #pragma unroll
        for (int w = 0; w < 4; ++w) {
            int mask = 8 >> w;
            #pragma unroll
            for (int idx = 0; idx < 16; ++idx) {
                if (idx & mask) continue;
                int i1 = idx | mask;
                float a0r = sr[idx], a0i = si[idx], a1r = sr[i1], a1i = si[i1];
                sr[idx] = c0 * a0r - s0 * a1r;  si[idx] = c0 * a0i - s0 * a1i;
                sr[i1]  = s0 * a0r + c0 * a1r;  si[i1]  = s0 * a0i + c0 * a1i;
            }
        }
        for (int layer = 0; layer < 2; ++layer) {
            #pragma unroll
            for (int w = 0; w < 4; ++w) {
                int gi = (layer * 4 + w) * 3;
                float phi = qp[gi], th = qp[gi + 1], om = qp[gi + 2];
                float hs = 0.5f * (phi + om), hd = 0.5f * (phi - om);
                float ct = cosf(0.5f * th), st = sinf(0.5f * th);
                float chs = cosf(hs), shs = sinf(hs);
                float chd = cosf(hd), shd = sinf(hd);
                float m00r = chs * ct,  m00i = -shs * ct;
                float m01r = -chd * st, m01i = -shd * st;
                float m10r = chd * st,  m10i = -shd * st;
                float m11r = chs * ct,  m11i = shs * ct;
                int mask = 8 >> w;
                #pragma unroll
                for (int idx = 0; idx < 16; ++idx) {
                    if (idx & mask) continue;
                    int i1 = idx | mask;
                    float a0r = sr[idx], a0i = si[idx], a1r = sr[i1], a1i = si[i1];
                    sr[idx] = m00r * a0r - m00i * a0i + m01r * a1r - m01i * a1i;
                    si[idx] = m00r * a0i + m00i * a0r + m01r * a1i + m01i * a1r;
                    sr[i1]  = m10r * a0r - m10i * a0i + m11r * a1r - m11i * a1i;
                    si[i1]  = m10r * a0i + m10i * a0r + m11r * a1i + m11i * a1r;
                }
            }
            #pragma unroll
            for (int cw = 0; cw < 3; ++cw) {
                int cm = 8 >> cw, tm = 8 >> (cw + 1);
                #pragma unroll
                for (int idx = 0; idx < 16; ++idx) {
                    if ((idx & cm) && !(idx & tm)) {
                        int i1 = idx | tm;
                        float tr = sr[idx]; sr[idx] = sr[i1]; sr[i1] = tr;
                        float ti = si[idx]; si[idx] = si[i1]; si[i1] = ti;
                    }
                }
            }
        }
        float q = 0.0f;
        #pragma unroll
        for (int idx = 0; idx < 16; ++idx) {
            float p2 = sr[idx] * sr[idx] + si[idx] * si[idx];
            q += (idx < 8) ? p2 : -p2;
        }
        float pr = 0.5f * (q + 1.0f);
        out[2 * b] = pr;
        out[2 * b + 1] = 1.0f - pr;
    }
}

extern "C" void kernel_launch(void* const* d_in, const int* in_sizes, int n_in,
                              void* d_out, int out_size, void* d_ws, size_t ws_size,
                              hipStream_t stream) {
    const float* inp = (const float*)d_in[0];
    const float* c1w = (const float*)d_in[1];
    const float* c1b = (const float*)d_in[2];
    const float* c2w = (const float*)d_in[3];
    const float* c2b = (const float*)d_in[4];
    const float* f1w = (const float*)d_in[5];
    const float* f1b = (const float*)d_in[6];
    const float* f2w = (const float*)d_in[7];
    const float* f2b = (const float*)d_in[8];
    const float* f3w = (const float*)d_in[9];
    const float* f3b = (const float*)d_in[10];
    const float* qp  = (const float*)d_in[11];
    float* out = (float*)d_out;
    float* ws = (float*)d_ws;

    // ws layout (floats):
    //   B (pool1 out) @ 0          : 128*6*123*123  = 11,619,072
    //   D (pool2 out) @ 11,619,072 : 128*15*61*61   =  7,144,320
    //   P (fc1 part.) @ 18,763,392 : SPLITK*128*120 =  3,932,160   (total 90.8 MB)
    float* B = ws;
    float* D = ws + 11619072;
    float* P = ws + 18763392;

    conv1f_k<<<dim3(4, 4, 128), 256, 0, stream>>>(inp, c1w, c1b, B);
    conv2f_k<<<dim3(5, 5, 128), 256, 0, stream>>>(B, c2w, c2b, D);
    fc1_k<<<dim3(SPLITK, 4), 256, 0, stream>>>(D, f1w, P);
    tail_k<<<128, 256, 0, stream>>>(P, f1b, f2w, f2b, f3w, f3b, qp, out);
}